// Round 11
// baseline (231.087 us; speedup 1.0000x reference)
//
#include <hip/hip_runtime.h>
#include <hip/hip_bf16.h>

#define B_ 8
#define T_ 1024
#define IN_DIM_ 16
#define D_ 256
#define H_ 8
#define L_ 4
#define DK_ 32
#define BT_ (B_*T_)
#define LDT 72    // padded LDS stride for GEMM A tiles
#define LDO 264   // padded LDS stride for outln A tile (256+8)

typedef __attribute__((ext_vector_type(8))) __bf16 bf16x8;
typedef __attribute__((ext_vector_type(8))) unsigned short u16x8;
typedef __attribute__((ext_vector_type(4))) unsigned short u16x4;
typedef __attribute__((ext_vector_type(4))) float f32x4;
typedef __attribute__((ext_vector_type(4))) unsigned int u32x4;

static __device__ __forceinline__ unsigned short f2bf(float f) {
  union { float f; unsigned int u; } c{f};
  unsigned int u = c.u;
  u += 0x7fff + ((u >> 16) & 1);
  return (unsigned short)(u >> 16);
}
static __device__ __forceinline__ bf16x8 as_bf(u16x8 v) {
  return __builtin_bit_cast(bf16x8, v);
}

// ------- weight prep: f32 W[z][K][N] -> bf16 fragment-tiled [z][N/16][K/32][16][32]
__global__ __launch_bounds__(64) void k_wprep_f(
    const float* __restrict__ in, unsigned short* __restrict__ out,
    int K, int N) {
  int nb = blockIdx.x, kb = blockIdx.y, z = blockIdx.z;
  const float* inz = in + (size_t)z * K * N;
  unsigned short* outz = out + (size_t)z * K * N;
  int lane = threadIdx.x;
  int li = lane & 15, g = lane >> 4;
  int n = nb * 16 + li;
  int k0 = kb * 32 + g * 8;
  u16x8 v;
  #pragma unroll
  for (int j = 0; j < 8; ++j) v[j] = f2bf(inz[(k0 + j) * N + n]);
  *(u16x8*)(outz + ((nb * (K >> 5) + kb) << 9) + li * 32 + g * 8) = v;
}

// ---------------- input projection: h = x@Wp + bp + pos ----------------
__global__ __launch_bounds__(256) void k_proj(
    const float* __restrict__ x, const float* __restrict__ Wp,
    const float* __restrict__ bp, const float* __restrict__ pos,
    float* __restrict__ h, unsigned short* __restrict__ hbf) {
  int row = blockIdx.x;            // bt
  int c = threadIdx.x;             // 0..255
  int t = row & (T_ - 1);
  float acc = bp[c] + pos[t * D_ + c];
  const float* xr = x + row * IN_DIM_;
  #pragma unroll
  for (int k = 0; k < IN_DIM_; ++k) acc += xr[k] * Wp[k * D_ + c];
  h[row * D_ + c] = acc;
  hbf[row * D_ + c] = f2bf(acc);
}

// ------------- QKV GEMM: BM=128, A staged in LDS, B fragment-tiled from L2 -----
__global__ __launch_bounds__(256) void k_gemm_qkv(
    const unsigned short* __restrict__ A,    // BT x 256 bf16
    const unsigned short* __restrict__ Btf,  // ftiled [48][8][16][32]
    const float* __restrict__ bias,          // 768
    unsigned short* __restrict__ qb, unsigned short* __restrict__ kb,
    unsigned short* __restrict__ vt) {
  __shared__ unsigned short As[128 * LDT];
  int row0 = blockIdx.x * 128;
  int tid = threadIdx.x;
  int lane = tid & 63, w = tid >> 6;
  int g = lane >> 4, li = lane & 15;
  int wr = (w >> 1) * 64, wc = (w & 1) * 32;
  int col0 = blockIdx.y * 64;
  f32x4 acc[4][2] = {};
  for (int k0 = 0; k0 < 256; k0 += 64) {
    __syncthreads();
    int r = tid >> 1, kk = (tid & 1) * 32;
    const unsigned short* src = A + (row0 + r) * 256 + k0 + kk;
    unsigned short* dst = As + r * LDT + kk;
    *(u16x8*)(dst)      = *(const u16x8*)(src);
    *(u16x8*)(dst + 8)  = *(const u16x8*)(src + 8);
    *(u16x8*)(dst + 16) = *(const u16x8*)(src + 16);
    *(u16x8*)(dst + 24) = *(const u16x8*)(src + 24);
    __syncthreads();
    #pragma unroll
    for (int ks = 0; ks < 2; ++ks) {
      int kblk = (k0 >> 5) + ks;
      bf16x8 af[4], bfr[2];
      #pragma unroll
      for (int m = 0; m < 4; ++m)
        af[m] = as_bf(*(const u16x8*)(As + (wr + m * 16 + li) * LDT + ks * 32 + g * 8));
      #pragma unroll
      for (int n = 0; n < 2; ++n) {
        int nblk = (blockIdx.y << 2) + ((w & 1) << 1) + n;
        bfr[n] = as_bf(*(const u16x8*)(Btf + ((nblk * 8 + kblk) << 9) + li * 32 + g * 8));
      }
      #pragma unroll
      for (int m = 0; m < 4; ++m)
        #pragma unroll
        for (int n = 0; n < 2; ++n)
          acc[m][n] = __builtin_amdgcn_mfma_f32_16x16x32_bf16(af[m], bfr[n], acc[m][n], 0, 0, 0);
    }
  }
  const float QSC = 0.25505654f;  // (1/sqrt(32)) * log2(e)
  #pragma unroll
  for (int m = 0; m < 4; ++m)
    #pragma unroll
    for (int n = 0; n < 2; ++n) {
      int c = col0 + wc + n * 16 + li;
      int rbase = row0 + wr + m * 16 + g * 4;
      int b = rbase >> 10, t = rbase & (T_ - 1);
      int s = c >> 8, rem = c & 255, hh = rem >> 5, dk = rem & 31;
      if (s == 0) {
        #pragma unroll
        for (int j = 0; j < 4; ++j) {
          float v = (acc[m][n][j] + bias[c]) * QSC;
          qb[(((b * H_ + hh) * T_) + t + j) * DK_ + dk] = f2bf(v);
        }
      } else if (s == 1) {
        #pragma unroll
        for (int j = 0; j < 4; ++j) {
          float v = acc[m][n][j] + bias[c];
          kb[(((b * H_ + hh) * T_) + t + j) * DK_ + dk] = f2bf(v);
        }
      } else {
        u16x4 pk;
        #pragma unroll
        for (int j = 0; j < 4; ++j) pk[j] = f2bf(acc[m][n][j] + bias[c]);
        // tiled V^T: [bh][t>>5][dk][t&31]
        *(u16x4*)(vt + (b * H_ + hh) * (DK_ * T_) +
                  ((t >> 5) * DK_ + dk) * 32 + (t & 31)) = pk;
      }
    }
}

// ---- attention: 32 q-rows/wave, 4-way split-K, register-double-buffered K/V ----
// Next tile's K/V loads are issued BEFORE the current tile's compute so the
// ~250cy L2 latency hides under the QK->exp->pack->PV chain (T14 idiom).
__global__ __launch_bounds__(256) void k_attn(
    const unsigned short* __restrict__ qb, const unsigned short* __restrict__ kb,
    const unsigned short* __restrict__ vt, unsigned short* __restrict__ ob) {
  __shared__ float Osh[4][32][33];
  __shared__ float Lsh[4][32];
  int bh = blockIdx.y;
  int tid = threadIdx.x, lane = tid & 63, w = tid >> 6;  // w = k-quarter
  int g = lane >> 4, li = lane & 15;
  int q0 = blockIdx.x * 32;
  const unsigned short* Qp = qb + (bh * T_ + q0) * DK_;
  const unsigned short* Kp = kb + bh * T_ * DK_;
  const unsigned short* Vt = vt + bh * DK_ * T_;
  bf16x8 aq0 = as_bf(*(const u16x8*)(Qp + li * DK_ + g * 8));
  bf16x8 aq1 = as_bf(*(const u16x8*)(Qp + (16 + li) * DK_ + g * 8));
  float l_run0 = 0.f, l_run1 = 0.f;
  f32x4 oacc0[2] = {}, oacc1[2] = {};
  const int kbeg = w * 256, kend = kbeg + 256;
  // prologue: load tile kbeg
  bf16x8 bk0 = as_bf(*(const u16x8*)(Kp + (kbeg + li) * DK_ + g * 8));
  bf16x8 bk1 = as_bf(*(const u16x8*)(Kp + (kbeg + 16 + li) * DK_ + g * 8));
  bf16x8 bv0 = as_bf(*(const u16x8*)(Vt + (kbeg >> 5) * (DK_ * 32) + li * 32 + g * 8));
  bf16x8 bv1 = as_bf(*(const u16x8*)(Vt + (kbeg >> 5) * (DK_ * 32) + (16 + li) * 32 + g * 8));
  for (int kt = kbeg; kt < kend; kt += 32) {
    // issue next tile's loads first (address wrapped on last iter; value unused)
    int ktn = (kt + 32 < kend) ? kt + 32 : kbeg;
    bf16x8 nk0 = as_bf(*(const u16x8*)(Kp + (ktn + li) * DK_ + g * 8));
    bf16x8 nk1 = as_bf(*(const u16x8*)(Kp + (ktn + 16 + li) * DK_ + g * 8));
    const unsigned short* nvt = Vt + (ktn >> 5) * (DK_ * 32);
    bf16x8 nv0 = as_bf(*(const u16x8*)(nvt + li * 32 + g * 8));
    bf16x8 nv1 = as_bf(*(const u16x8*)(nvt + (16 + li) * 32 + g * 8));
    // compute on current (resident) tile
    f32x4 s0 = {}, s1 = {}, t0 = {}, t1 = {};
    __builtin_amdgcn_s_setprio(1);
    s0 = __builtin_amdgcn_mfma_f32_16x16x32_bf16(bk0, aq0, s0, 0, 0, 0);
    s1 = __builtin_amdgcn_mfma_f32_16x16x32_bf16(bk1, aq0, s1, 0, 0, 0);
    t0 = __builtin_amdgcn_mfma_f32_16x16x32_bf16(bk0, aq1, t0, 0, 0, 0);
    t1 = __builtin_amdgcn_mfma_f32_16x16x32_bf16(bk1, aq1, t1, 0, 0, 0);
    __builtin_amdgcn_s_setprio(0);
    {
      float p0[4], p1[4];
      #pragma unroll
      for (int j = 0; j < 4; ++j) {
        p0[j] = __builtin_amdgcn_exp2f(s0[j]);
        p1[j] = __builtin_amdgcn_exp2f(s1[j]);
      }
      l_run0 += ((p0[0] + p0[1]) + (p0[2] + p0[3])) +
                ((p1[0] + p1[1]) + (p1[2] + p1[3]));
      unsigned int c0, c1, c2, c3;
      asm("v_cvt_pk_bf16_f32 %0, %1, %2" : "=v"(c0) : "v"(p0[0]), "v"(p0[1]));
      asm("v_cvt_pk_bf16_f32 %0, %1, %2" : "=v"(c1) : "v"(p0[2]), "v"(p0[3]));
      asm("v_cvt_pk_bf16_f32 %0, %1, %2" : "=v"(c2) : "v"(p1[0]), "v"(p1[1]));
      asm("v_cvt_pk_bf16_f32 %0, %1, %2" : "=v"(c3) : "v"(p1[2]), "v"(p1[3]));
      asm("v_permlane32_swap_b32 %0, %1" : "+v"(c0), "+v"(c2));
      asm("v_permlane32_swap_b32 %0, %1" : "+v"(c1), "+v"(c3));
      asm("v_permlane16_swap_b32 %0, %1" : "+v"(c0), "+v"(c2));
      asm("v_permlane16_swap_b32 %0, %1" : "+v"(c1), "+v"(c3));
      u32x4 paw; paw[0] = c0; paw[1] = c1; paw[2] = c2; paw[3] = c3;
      bf16x8 pa = __builtin_bit_cast(bf16x8, paw);
      __builtin_amdgcn_s_setprio(1);
      oacc0[0] = __builtin_amdgcn_mfma_f32_16x16x32_bf16(pa, bv0, oacc0[0], 0, 0, 0);
      oacc0[1] = __builtin_amdgcn_mfma_f32_16x16x32_bf16(pa, bv1, oacc0[1], 0, 0, 0);
      __builtin_amdgcn_s_setprio(0);
    }
    {
      float p0[4], p1[4];
      #pragma unroll
      for (int j = 0; j < 4; ++j) {
        p0[j] = __builtin_amdgcn_exp2f(t0[j]);
        p1[j] = __builtin_amdgcn_exp2f(t1[j]);
      }
      l_run1 += ((p0[0] + p0[1]) + (p0[2] + p0[3])) +
                ((p1[0] + p1[1]) + (p1[2] + p1[3]));
      unsigned int c0, c1, c2, c3;
      asm("v_cvt_pk_bf16_f32 %0, %1, %2" : "=v"(c0) : "v"(p0[0]), "v"(p0[1]));
      asm("v_cvt_pk_bf16_f32 %0, %1, %2" : "=v"(c1) : "v"(p0[2]), "v"(p0[3]));
      asm("v_cvt_pk_bf16_f32 %0, %1, %2" : "=v"(c2) : "v"(p1[0]), "v"(p1[1]));
      asm("v_cvt_pk_bf16_f32 %0, %1, %2" : "=v"(c3) : "v"(p1[2]), "v"(p1[3]));
      asm("v_permlane32_swap_b32 %0, %1" : "+v"(c0), "+v"(c2));
      asm("v_permlane32_swap_b32 %0, %1" : "+v"(c1), "+v"(c3));
      asm("v_permlane16_swap_b32 %0, %1" : "+v"(c0), "+v"(c2));
      asm("v_permlane16_swap_b32 %0, %1" : "+v"(c1), "+v"(c3));
      u32x4 paw; paw[0] = c0; paw[1] = c1; paw[2] = c2; paw[3] = c3;
      bf16x8 pa = __builtin_bit_cast(bf16x8, paw);
      __builtin_amdgcn_s_setprio(1);
      oacc1[0] = __builtin_amdgcn_mfma_f32_16x16x32_bf16(pa, bv0, oacc1[0], 0, 0, 0);
      oacc1[1] = __builtin_amdgcn_mfma_f32_16x16x32_bf16(pa, bv1, oacc1[1], 0, 0, 0);
      __builtin_amdgcn_s_setprio(0);
    }
    bk0 = nk0; bk1 = nk1; bv0 = nv0; bv1 = nv1;
  }
  l_run0 += __shfl_xor(l_run0, 16);
  l_run0 += __shfl_xor(l_run0, 32);
  l_run1 += __shfl_xor(l_run1, 16);
  l_run1 += __shfl_xor(l_run1, 32);
  if (g == 0) { Lsh[w][li] = l_run0; Lsh[w][16 + li] = l_run1; }
  #pragma unroll
  for (int dh = 0; dh < 2; ++dh)
    #pragma unroll
    for (int j = 0; j < 4; ++j) {
      Osh[w][g * 4 + j][dh * 16 + li] = oacc0[dh][j];
      Osh[w][16 + g * 4 + j][dh * 16 + li] = oacc1[dh][j];
    }
  __syncthreads();
  if (tid < 128) {
    int q = tid & 31, dk0 = (tid >> 5) * 8;
    float l = (Lsh[0][q] + Lsh[1][q]) + (Lsh[2][q] + Lsh[3][q]);
    float rl = 1.0f / l;
    int b = bh >> 3, hh = bh & 7;
    u16x8 outv;
    #pragma unroll
    for (int i = 0; i < 8; ++i) {
      float o = (Osh[0][q][dk0 + i] + Osh[1][q][dk0 + i]) +
                (Osh[2][q][dk0 + i] + Osh[3][q][dk0 + i]);
      outv[i] = f2bf(o * rl);
    }
    *(u16x8*)(ob + ((b * T_ + q0 + q) * H_ + hh) * DK_ + dk0) = outv;
  }
}

// ------- fused out-proj + residual + LayerNorm: h = LN(ob@Wout+bout+h) -------
__global__ __launch_bounds__(256) void k_outln(
    const unsigned short* __restrict__ A,    // BT x 256 bf16 (attn out)
    const unsigned short* __restrict__ Btf,  // ftiled [16][8][16][32]
    const float* __restrict__ bias,          // 256
    const float* __restrict__ gg, const float* __restrict__ bb,
    float* __restrict__ h,                   // in: residual, out: LN result
    unsigned short* __restrict__ hbf) {
  __shared__ unsigned short Asp[32 * LDO];
  __shared__ float Ssh[2][2][16], Qsh[2][2][16];
  int tid = threadIdx.x, lane = tid & 63, w = tid >> 6;
  int g = lane >> 4, li = lane & 15;
  int rg = w >> 1, ch = w & 1;
  int row0 = blockIdx.x * 32;
  int c0 = ch * 128;
  {  // stage A tile 32x256 coalesced
    int r = tid >> 3, kk = (tid & 7) * 32;
    const unsigned short* src = A + (row0 + r) * 256 + kk;
    unsigned short* dst = Asp + r * LDO + kk;
    *(u16x8*)(dst)      = *(const u16x8*)(src);
    *(u16x8*)(dst + 8)  = *(const u16x8*)(src + 8);
    *(u16x8*)(dst + 16) = *(const u16x8*)(src + 16);
    *(u16x8*)(dst + 24) = *(const u16x8*)(src + 24);
  }
  __syncthreads();
  int rowb = rg * 16;
  f32x4 acc[8] = {};
  for (int k0 = 0; k0 < 256; k0 += 32) {
    int kblk = k0 >> 5;
    bf16x8 af = as_bf(*(const u16x8*)(Asp + (rowb + li) * LDO + k0 + g * 8));
    #pragma unroll
    for (int n = 0; n < 8; ++n) {
      int nblk = ch * 8 + n;
      bf16x8 bf = as_bf(*(const u16x8*)(Btf + ((nblk * 8 + kblk) << 9) + li * 32 + g * 8));
      acc[n] = __builtin_amdgcn_mfma_f32_16x16x32_bf16(af, bf, acc[n], 0, 0, 0);
    }
  }
  int row0w = row0 + rowb;
  float uv[8][4];
  float s[4] = {0.f, 0.f, 0.f, 0.f}, q[4] = {0.f, 0.f, 0.f, 0.f};
  #pragma unroll
  for (int n = 0; n < 8; ++n) {
    int c = c0 + n * 16 + li;
    float bs = bias[c];
    #pragma unroll
    for (int j = 0; j < 4; ++j) {
      int r = row0w + g * 4 + j;
      float v = acc[n][j] + bs + h[r * 256 + c];
      uv[n][j] = v;
      s[j] += v; q[j] += v * v;
    }
  }
  #pragma unroll
  for (int j = 0; j < 4; ++j) {
    #pragma unroll
    for (int o = 1; o < 16; o <<= 1) {
      s[j] += __shfl_xor(s[j], o);
      q[j] += __shfl_xor(q[j], o);
    }
  }
  if (li == 0) {
    #pragma unroll
    for (int j = 0; j < 4; ++j) {
      Ssh[rg][ch][g * 4 + j] = s[j];
      Qsh[rg][ch][g * 4 + j] = q[j];
    }
  }
  __syncthreads();
  #pragma unroll
  for (int j = 0; j < 4; ++j) {
    int r = g * 4 + j;
    float st = Ssh[rg][0][r] + Ssh[rg][1][r];
    float qt = Qsh[rg][0][r] + Qsh[rg][1][r];
    float mean = st * (1.0f / D_);
    float var = qt * (1.0f / D_) - mean * mean;
    float rstd = rsqrtf(var + 1e-5f);
    s[j] = mean; q[j] = rstd;
  }
  #pragma unroll
  for (int n = 0; n < 8; ++n) {
    int c = c0 + n * 16 + li;
    float gv = gg[c], bv = bb[c];
    #pragma unroll
    for (int j = 0; j < 4; ++j) {
      int r = row0w + g * 4 + j;
      float y = (uv[n][j] - s[j]) * q[j] * gv + bv;
      h[r * 256 + c] = y;
      hbf[r * 256 + c] = f2bf(y);
    }
  }
}

// ---------------- final: out = h[:, -1, :] @ Wo + bo ----------------
__global__ void k_final(const float* __restrict__ h, const float* __restrict__ Wo,
                        const float* __restrict__ bo, float* __restrict__ out) {
  int tid = threadIdx.x;
  if (tid >= B_ * 3) return;
  int b = tid / 3, j = tid % 3;
  const float* hr = h + (b * T_ + (T_ - 1)) * D_;
  float acc = bo[j];
  for (int k = 0; k < D_; ++k) acc += hr[k] * Wo[k * 3 + j];
  out[tid] = acc;
}

extern "C" void kernel_launch(void* const* d_in, const int* in_sizes, int n_in,
                              void* d_out, int out_size, void* d_ws, size_t ws_size,
                              hipStream_t stream) {
  const float* x    = (const float*)d_in[0];
  const float* Wp   = (const float*)d_in[1];
  const float* bp   = (const float*)d_in[2];
  const float* pos  = (const float*)d_in[3];
  const float* Wqkv = (const float*)d_in[4];
  const float* bqkv = (const float*)d_in[5];
  const float* Wout = (const float*)d_in[6];
  const float* bout = (const float*)d_in[7];
  const float* ln_g = (const float*)d_in[8];
  const float* ln_b = (const float*)d_in[9];
  const float* Wo   = (const float*)d_in[10];
  const float* bo   = (const float*)d_in[11];

  char* ws = (char*)d_ws;
  float* h            = (float*)(ws);                        // 8 MB
  unsigned short* hbf = (unsigned short*)(ws + (16u << 20)); // 4 MB
  unsigned short* qb  = (unsigned short*)(ws + (20u << 20)); // 4 MB
  unsigned short* kb  = (unsigned short*)(ws + (24u << 20)); // 4 MB
  unsigned short* vt  = (unsigned short*)(ws + (28u << 20)); // 4 MB (tiled V^T)
  unsigned short* ob  = (unsigned short*)(ws + (32u << 20)); // 4 MB
  unsigned short* WqkvT = (unsigned short*)(ws + (36u << 20)); // 1.5 MB ftiled
  unsigned short* WoutT = (unsigned short*)(ws + (38u << 20)); // 0.5 MB ftiled

  k_wprep_f<<<dim3(48, 8, 4), 64, 0, stream>>>(Wqkv, WqkvT, 256, 768);
  k_wprep_f<<<dim3(16, 8, 4), 64, 0, stream>>>(Wout, WoutT, 256, 256);
  k_proj<<<BT_, 256, 0, stream>>>(x, Wp, bp, pos, h, hbf);
  for (int l = 0; l < L_; ++l) {
    k_gemm_qkv<<<dim3(BT_ / 128, 12), 256, 0, stream>>>(
        hbf, WqkvT + l * 768 * 256, bqkv + l * 768, qb, kb, vt);
    k_attn<<<dim3(T_ / 32, B_ * H_), 256, 0, stream>>>(qb, kb, vt, ob);
    k_outln<<<BT_ / 32, 256, 0, stream>>>(
        ob, WoutT + l * 256 * 256, bout + l * 256,
        ln_g + l * 256, ln_b + l * 256, h, hbf);
  }
  k_final<<<1, 64, 0, stream>>>(h, Wo, bo, (float*)d_out);
}

// Round 12
// 205.692 us; speedup vs baseline: 1.1235x; 1.1235x over previous
//
#include <hip/hip_runtime.h>
#include <hip/hip_bf16.h>

#define B_ 8
#define T_ 1024
#define IN_DIM_ 16
#define D_ 256
#define H_ 8
#define L_ 4
#define DK_ 32
#define BT_ (B_*T_)
#define LDT 72    // padded LDS stride for GEMM A tiles
#define LDO 264   // padded LDS stride for outln A tile (256+8)

typedef __attribute__((ext_vector_type(8))) __bf16 bf16x8;
typedef __attribute__((ext_vector_type(8))) unsigned short u16x8;
typedef __attribute__((ext_vector_type(4))) unsigned short u16x4;
typedef __attribute__((ext_vector_type(4))) float f32x4;
typedef __attribute__((ext_vector_type(4))) unsigned int u32x4;

static __device__ __forceinline__ unsigned short f2bf(float f) {
  union { float f; unsigned int u; } c{f};
  unsigned int u = c.u;
  u += 0x7fff + ((u >> 16) & 1);
  return (unsigned short)(u >> 16);
}
static __device__ __forceinline__ float bf2f(unsigned short s) {
  union { unsigned int u; float f; } c{(unsigned int)s << 16};
  return c.f;
}
static __device__ __forceinline__ bf16x8 as_bf(u16x8 v) {
  return __builtin_bit_cast(bf16x8, v);
}

// ------- weight prep: f32 W[z][K][N] -> bf16 fragment-tiled [z][N/16][K/32][16][32]
__global__ __launch_bounds__(64) void k_wprep_f(
    const float* __restrict__ in, unsigned short* __restrict__ out,
    int K, int N) {
  int nb = blockIdx.x, kb = blockIdx.y, z = blockIdx.z;
  const float* inz = in + (size_t)z * K * N;
  unsigned short* outz = out + (size_t)z * K * N;
  int lane = threadIdx.x;
  int li = lane & 15, g = lane >> 4;
  int n = nb * 16 + li;
  int k0 = kb * 32 + g * 8;
  u16x8 v;
  #pragma unroll
  for (int j = 0; j < 8; ++j) v[j] = f2bf(inz[(k0 + j) * N + n]);
  *(u16x8*)(outz + ((nb * (K >> 5) + kb) << 9) + li * 32 + g * 8) = v;
}

// ---------------- input projection: hbf = bf16(x@Wp + bp + pos) ----------------
__global__ __launch_bounds__(256) void k_proj(
    const float* __restrict__ x, const float* __restrict__ Wp,
    const float* __restrict__ bp, const float* __restrict__ pos,
    unsigned short* __restrict__ hbf) {
  int row = blockIdx.x;            // bt
  int c = threadIdx.x;             // 0..255
  int t = row & (T_ - 1);
  float acc = bp[c] + pos[t * D_ + c];
  const float* xr = x + row * IN_DIM_;
  #pragma unroll
  for (int k = 0; k < IN_DIM_; ++k) acc += xr[k] * Wp[k * D_ + c];
  hbf[row * D_ + c] = f2bf(acc);
}

// ------------- QKV GEMM: BM=128, A staged in LDS, B fragment-tiled from L2 -----
__global__ __launch_bounds__(256) void k_gemm_qkv(
    const unsigned short* __restrict__ A,    // BT x 256 bf16
    const unsigned short* __restrict__ Btf,  // ftiled [48][8][16][32]
    const float* __restrict__ bias,          // 768
    unsigned short* __restrict__ qb, unsigned short* __restrict__ kb,
    unsigned short* __restrict__ vt) {
  __shared__ unsigned short As[128 * LDT];
  int row0 = blockIdx.x * 128;
  int tid = threadIdx.x;
  int lane = tid & 63, w = tid >> 6;
  int g = lane >> 4, li = lane & 15;
  int wr = (w >> 1) * 64, wc = (w & 1) * 32;
  int col0 = blockIdx.y * 64;
  f32x4 acc[4][2] = {};
  for (int k0 = 0; k0 < 256; k0 += 64) {
    __syncthreads();
    int r = tid >> 1, kk = (tid & 1) * 32;
    const unsigned short* src = A + (row0 + r) * 256 + k0 + kk;
    unsigned short* dst = As + r * LDT + kk;
    *(u16x8*)(dst)      = *(const u16x8*)(src);
    *(u16x8*)(dst + 8)  = *(const u16x8*)(src + 8);
    *(u16x8*)(dst + 16) = *(const u16x8*)(src + 16);
    *(u16x8*)(dst + 24) = *(const u16x8*)(src + 24);
    __syncthreads();
    #pragma unroll
    for (int ks = 0; ks < 2; ++ks) {
      int kblk = (k0 >> 5) + ks;
      bf16x8 af[4], bfr[2];
      #pragma unroll
      for (int m = 0; m < 4; ++m)
        af[m] = as_bf(*(const u16x8*)(As + (wr + m * 16 + li) * LDT + ks * 32 + g * 8));
      #pragma unroll
      for (int n = 0; n < 2; ++n) {
        int nblk = (blockIdx.y << 2) + ((w & 1) << 1) + n;
        bfr[n] = as_bf(*(const u16x8*)(Btf + ((nblk * 8 + kblk) << 9) + li * 32 + g * 8));
      }
      #pragma unroll
      for (int m = 0; m < 4; ++m)
        #pragma unroll
        for (int n = 0; n < 2; ++n)
          acc[m][n] = __builtin_amdgcn_mfma_f32_16x16x32_bf16(af[m], bfr[n], acc[m][n], 0, 0, 0);
    }
  }
  const float QSC = 0.25505654f;  // (1/sqrt(32)) * log2(e)
  #pragma unroll
  for (int m = 0; m < 4; ++m)
    #pragma unroll
    for (int n = 0; n < 2; ++n) {
      int c = col0 + wc + n * 16 + li;
      int rbase = row0 + wr + m * 16 + g * 4;
      int b = rbase >> 10, t = rbase & (T_ - 1);
      int s = c >> 8, rem = c & 255, hh = rem >> 5, dk = rem & 31;
      if (s == 0) {
        #pragma unroll
        for (int j = 0; j < 4; ++j) {
          float v = (acc[m][n][j] + bias[c]) * QSC;
          qb[(((b * H_ + hh) * T_) + t + j) * DK_ + dk] = f2bf(v);
        }
      } else if (s == 1) {
        #pragma unroll
        for (int j = 0; j < 4; ++j) {
          float v = acc[m][n][j] + bias[c];
          kb[(((b * H_ + hh) * T_) + t + j) * DK_ + dk] = f2bf(v);
        }
      } else {
        u16x4 pk;
        #pragma unroll
        for (int j = 0; j < 4; ++j) pk[j] = f2bf(acc[m][n][j] + bias[c]);
        // tiled V^T: [bh][t>>5][dk][t&31]
        *(u16x4*)(vt + (b * H_ + hh) * (DK_ * T_) +
                  ((t >> 5) * DK_ + dk) * 32 + (t & 31)) = pk;
      }
    }
}

// ---- attention: 32 q-rows/wave (2 Q frags), 4-wave 4-way split-K (R10-exact) ----
__global__ __launch_bounds__(256) void k_attn(
    const unsigned short* __restrict__ qb, const unsigned short* __restrict__ kb,
    const unsigned short* __restrict__ vt, unsigned short* __restrict__ ob) {
  __shared__ float Osh[4][32][33];
  __shared__ float Lsh[4][32];
  int bh = blockIdx.y;
  int tid = threadIdx.x, lane = tid & 63, w = tid >> 6;  // w = k-quarter
  int g = lane >> 4, li = lane & 15;
  int q0 = blockIdx.x * 32;
  const unsigned short* Qp = qb + (bh * T_ + q0) * DK_;
  const unsigned short* Kp = kb + bh * T_ * DK_;
  const unsigned short* Vt = vt + bh * DK_ * T_;
  bf16x8 aq0 = as_bf(*(const u16x8*)(Qp + li * DK_ + g * 8));
  bf16x8 aq1 = as_bf(*(const u16x8*)(Qp + (16 + li) * DK_ + g * 8));
  float l_run0 = 0.f, l_run1 = 0.f;
  f32x4 oacc0[2] = {}, oacc1[2] = {};
  for (int kt = w * 256; kt < (w + 1) * 256; kt += 32) {
    bf16x8 bk0 = as_bf(*(const u16x8*)(Kp + (kt + li) * DK_ + g * 8));
    bf16x8 bk1 = as_bf(*(const u16x8*)(Kp + (kt + 16 + li) * DK_ + g * 8));
    const unsigned short* vtile = Vt + (kt >> 5) * (DK_ * 32);
    bf16x8 bv0 = as_bf(*(const u16x8*)(vtile + li * 32 + g * 8));
    bf16x8 bv1 = as_bf(*(const u16x8*)(vtile + (16 + li) * 32 + g * 8));
    f32x4 s0 = {}, s1 = {}, t0 = {}, t1 = {};
    __builtin_amdgcn_s_setprio(1);
    s0 = __builtin_amdgcn_mfma_f32_16x16x32_bf16(bk0, aq0, s0, 0, 0, 0);
    s1 = __builtin_amdgcn_mfma_f32_16x16x32_bf16(bk1, aq0, s1, 0, 0, 0);
    t0 = __builtin_amdgcn_mfma_f32_16x16x32_bf16(bk0, aq1, t0, 0, 0, 0);
    t1 = __builtin_amdgcn_mfma_f32_16x16x32_bf16(bk1, aq1, t1, 0, 0, 0);
    __builtin_amdgcn_s_setprio(0);
    {
      float p0[4], p1[4];
      #pragma unroll
      for (int j = 0; j < 4; ++j) {
        p0[j] = __builtin_amdgcn_exp2f(s0[j]);
        p1[j] = __builtin_amdgcn_exp2f(s1[j]);
      }
      l_run0 += ((p0[0] + p0[1]) + (p0[2] + p0[3])) +
                ((p1[0] + p1[1]) + (p1[2] + p1[3]));
      unsigned int c0, c1, c2, c3;
      asm("v_cvt_pk_bf16_f32 %0, %1, %2" : "=v"(c0) : "v"(p0[0]), "v"(p0[1]));
      asm("v_cvt_pk_bf16_f32 %0, %1, %2" : "=v"(c1) : "v"(p0[2]), "v"(p0[3]));
      asm("v_cvt_pk_bf16_f32 %0, %1, %2" : "=v"(c2) : "v"(p1[0]), "v"(p1[1]));
      asm("v_cvt_pk_bf16_f32 %0, %1, %2" : "=v"(c3) : "v"(p1[2]), "v"(p1[3]));
      asm("v_permlane32_swap_b32 %0, %1" : "+v"(c0), "+v"(c2));
      asm("v_permlane32_swap_b32 %0, %1" : "+v"(c1), "+v"(c3));
      asm("v_permlane16_swap_b32 %0, %1" : "+v"(c0), "+v"(c2));
      asm("v_permlane16_swap_b32 %0, %1" : "+v"(c1), "+v"(c3));
      u32x4 paw; paw[0] = c0; paw[1] = c1; paw[2] = c2; paw[3] = c3;
      bf16x8 pa = __builtin_bit_cast(bf16x8, paw);
      __builtin_amdgcn_s_setprio(1);
      oacc0[0] = __builtin_amdgcn_mfma_f32_16x16x32_bf16(pa, bv0, oacc0[0], 0, 0, 0);
      oacc0[1] = __builtin_amdgcn_mfma_f32_16x16x32_bf16(pa, bv1, oacc0[1], 0, 0, 0);
      __builtin_amdgcn_s_setprio(0);
    }
    {
      float p0[4], p1[4];
      #pragma unroll
      for (int j = 0; j < 4; ++j) {
        p0[j] = __builtin_amdgcn_exp2f(t0[j]);
        p1[j] = __builtin_amdgcn_exp2f(t1[j]);
      }
      l_run1 += ((p0[0] + p0[1]) + (p0[2] + p0[3])) +
                ((p1[0] + p1[1]) + (p1[2] + p1[3]));
      unsigned int c0, c1, c2, c3;
      asm("v_cvt_pk_bf16_f32 %0, %1, %2" : "=v"(c0) : "v"(p0[0]), "v"(p0[1]));
      asm("v_cvt_pk_bf16_f32 %0, %1, %2" : "=v"(c1) : "v"(p0[2]), "v"(p0[3]));
      asm("v_cvt_pk_bf16_f32 %0, %1, %2" : "=v"(c2) : "v"(p1[0]), "v"(p1[1]));
      asm("v_cvt_pk_bf16_f32 %0, %1, %2" : "=v"(c3) : "v"(p1[2]), "v"(p1[3]));
      asm("v_permlane32_swap_b32 %0, %1" : "+v"(c0), "+v"(c2));
      asm("v_permlane32_swap_b32 %0, %1" : "+v"(c1), "+v"(c3));
      asm("v_permlane16_swap_b32 %0, %1" : "+v"(c0), "+v"(c2));
      asm("v_permlane16_swap_b32 %0, %1" : "+v"(c1), "+v"(c3));
      u32x4 paw; paw[0] = c0; paw[1] = c1; paw[2] = c2; paw[3] = c3;
      bf16x8 pa = __builtin_bit_cast(bf16x8, paw);
      __builtin_amdgcn_s_setprio(1);
      oacc1[0] = __builtin_amdgcn_mfma_f32_16x16x32_bf16(pa, bv0, oacc1[0], 0, 0, 0);
      oacc1[1] = __builtin_amdgcn_mfma_f32_16x16x32_bf16(pa, bv1, oacc1[1], 0, 0, 0);
      __builtin_amdgcn_s_setprio(0);
    }
  }
  l_run0 += __shfl_xor(l_run0, 16);
  l_run0 += __shfl_xor(l_run0, 32);
  l_run1 += __shfl_xor(l_run1, 16);
  l_run1 += __shfl_xor(l_run1, 32);
  if (g == 0) { Lsh[w][li] = l_run0; Lsh[w][16 + li] = l_run1; }
  #pragma unroll
  for (int dh = 0; dh < 2; ++dh)
    #pragma unroll
    for (int j = 0; j < 4; ++j) {
      Osh[w][g * 4 + j][dh * 16 + li] = oacc0[dh][j];
      Osh[w][16 + g * 4 + j][dh * 16 + li] = oacc1[dh][j];
    }
  __syncthreads();
  if (tid < 128) {
    int q = tid & 31, dk0 = (tid >> 5) * 8;
    float l = (Lsh[0][q] + Lsh[1][q]) + (Lsh[2][q] + Lsh[3][q]);
    float rl = 1.0f / l;
    int b = bh >> 3, hh = bh & 7;
    u16x8 outv;
    #pragma unroll
    for (int i = 0; i < 8; ++i) {
      float o = (Osh[0][q][dk0 + i] + Osh[1][q][dk0 + i]) +
                (Osh[2][q][dk0 + i] + Osh[3][q][dk0 + i]);
      outv[i] = f2bf(o * rl);
    }
    *(u16x8*)(ob + ((b * T_ + q0 + q) * H_ + hh) * DK_ + dk0) = outv;
  }
}

// -- fused out-proj + residual + LayerNorm, bf16 residual: hbf = LN(ob@W+b+hbf) --
__global__ __launch_bounds__(256) void k_outln(
    const unsigned short* __restrict__ A,    // BT x 256 bf16 (attn out)
    const unsigned short* __restrict__ Btf,  // ftiled [16][8][16][32]
    const float* __restrict__ bias,          // 256
    const float* __restrict__ gg, const float* __restrict__ bb,
    unsigned short* __restrict__ hbf) {      // in: residual, out: LN result
  __shared__ unsigned short Asp[32 * LDO];
  __shared__ float Ssh[2][2][16], Qsh[2][2][16];
  int tid = threadIdx.x, lane = tid & 63, w = tid >> 6;
  int g = lane >> 4, li = lane & 15;
  int rg = w >> 1, ch = w & 1;
  int row0 = blockIdx.x * 32;
  int c0 = ch * 128;
  {  // stage A tile 32x256 coalesced
    int r = tid >> 3, kk = (tid & 7) * 32;
    const unsigned short* src = A + (row0 + r) * 256 + kk;
    unsigned short* dst = Asp + r * LDO + kk;
    *(u16x8*)(dst)      = *(const u16x8*)(src);
    *(u16x8*)(dst + 8)  = *(const u16x8*)(src + 8);
    *(u16x8*)(dst + 16) = *(const u16x8*)(src + 16);
    *(u16x8*)(dst + 24) = *(const u16x8*)(src + 24);
  }
  __syncthreads();
  int rowb = rg * 16;
  f32x4 acc[8] = {};
  for (int k0 = 0; k0 < 256; k0 += 32) {
    int kblk = k0 >> 5;
    bf16x8 af = as_bf(*(const u16x8*)(Asp + (rowb + li) * LDO + k0 + g * 8));
    #pragma unroll
    for (int n = 0; n < 8; ++n) {
      int nblk = ch * 8 + n;
      bf16x8 bf = as_bf(*(const u16x8*)(Btf + ((nblk * 8 + kblk) << 9) + li * 32 + g * 8));
      acc[n] = __builtin_amdgcn_mfma_f32_16x16x32_bf16(af, bf, acc[n], 0, 0, 0);
    }
  }
  int row0w = row0 + rowb;
  float uv[8][4];
  float s[4] = {0.f, 0.f, 0.f, 0.f}, q[4] = {0.f, 0.f, 0.f, 0.f};
  #pragma unroll
  for (int n = 0; n < 8; ++n) {
    int c = c0 + n * 16 + li;
    float bs = bias[c];
    #pragma unroll
    for (int j = 0; j < 4; ++j) {
      int r = row0w + g * 4 + j;
      float v = acc[n][j] + bs + bf2f(hbf[r * 256 + c]);
      uv[n][j] = v;
      s[j] += v; q[j] += v * v;
    }
  }
  #pragma unroll
  for (int j = 0; j < 4; ++j) {
    #pragma unroll
    for (int o = 1; o < 16; o <<= 1) {
      s[j] += __shfl_xor(s[j], o);
      q[j] += __shfl_xor(q[j], o);
    }
  }
  if (li == 0) {
    #pragma unroll
    for (int j = 0; j < 4; ++j) {
      Ssh[rg][ch][g * 4 + j] = s[j];
      Qsh[rg][ch][g * 4 + j] = q[j];
    }
  }
  __syncthreads();
  #pragma unroll
  for (int j = 0; j < 4; ++j) {
    int r = g * 4 + j;
    float st = Ssh[rg][0][r] + Ssh[rg][1][r];
    float qt = Qsh[rg][0][r] + Qsh[rg][1][r];
    float mean = st * (1.0f / D_);
    float var = qt * (1.0f / D_) - mean * mean;
    float rstd = rsqrtf(var + 1e-5f);
    s[j] = mean; q[j] = rstd;
  }
  #pragma unroll
  for (int n = 0; n < 8; ++n) {
    int c = c0 + n * 16 + li;
    float gv = gg[c], bv = bb[c];
    #pragma unroll
    for (int j = 0; j < 4; ++j) {
      int r = row0w + g * 4 + j;
      float y = (uv[n][j] - s[j]) * q[j] * gv + bv;
      hbf[r * 256 + c] = f2bf(y);
    }
  }
}

// ---------------- final: out = h[:, -1, :] @ Wo + bo (h from bf16) ----------------
__global__ void k_final(const unsigned short* __restrict__ hbf,
                        const float* __restrict__ Wo,
                        const float* __restrict__ bo, float* __restrict__ out) {
  int tid = threadIdx.x;
  if (tid >= B_ * 3) return;
  int b = tid / 3, j = tid % 3;
  const unsigned short* hr = hbf + (b * T_ + (T_ - 1)) * D_;
  float acc = bo[j];
  for (int k = 0; k < D_; ++k) acc += bf2f(hr[k]) * Wo[k * 3 + j];
  out[tid] = acc;
}

extern "C" void kernel_launch(void* const* d_in, const int* in_sizes, int n_in,
                              void* d_out, int out_size, void* d_ws, size_t ws_size,
                              hipStream_t stream) {
  const float* x    = (const float*)d_in[0];
  const float* Wp   = (const float*)d_in[1];
  const float* bp   = (const float*)d_in[2];
  const float* pos  = (const float*)d_in[3];
  const float* Wqkv = (const float*)d_in[4];
  const float* bqkv = (const float*)d_in[5];
  const float* Wout = (const float*)d_in[6];
  const float* bout = (const float*)d_in[7];
  const float* ln_g = (const float*)d_in[8];
  const float* ln_b = (const float*)d_in[9];
  const float* Wo   = (const float*)d_in[10];
  const float* bo   = (const float*)d_in[11];

  char* ws = (char*)d_ws;
  unsigned short* hbf = (unsigned short*)(ws);               // 4 MB (bf16 h)
  unsigned short* qb  = (unsigned short*)(ws + (4u << 20));  // 4 MB
  unsigned short* kb  = (unsigned short*)(ws + (8u << 20));  // 4 MB
  unsigned short* vt  = (unsigned short*)(ws + (12u << 20)); // 4 MB (tiled V^T)
  unsigned short* ob  = (unsigned short*)(ws + (16u << 20)); // 4 MB
  unsigned short* WqkvT = (unsigned short*)(ws + (20u << 20)); // 1.5 MB ftiled
  unsigned short* WoutT = (unsigned short*)(ws + (22u << 20)); // 0.5 MB ftiled

  k_wprep_f<<<dim3(48, 8, 4), 64, 0, stream>>>(Wqkv, WqkvT, 256, 768);
  k_wprep_f<<<dim3(16, 8, 4), 64, 0, stream>>>(Wout, WoutT, 256, 256);
  k_proj<<<BT_, 256, 0, stream>>>(x, Wp, bp, pos, hbf);
  for (int l = 0; l < L_; ++l) {
    k_gemm_qkv<<<dim3(BT_ / 128, 12), 256, 0, stream>>>(
        hbf, WqkvT + l * 768 * 256, bqkv + l * 768, qb, kb, vt);
    k_attn<<<dim3(T_ / 32, B_ * H_), 256, 0, stream>>>(qb, kb, vt, ob);
    k_outln<<<BT_ / 32, 256, 0, stream>>>(
        ob, WoutT + l * 256 * 256, bout + l * 256,
        ln_g + l * 256, ln_b + l * 256, hbf);
  }
  k_final<<<1, 64, 0, stream>>>(hbf, Wo, bo, (float*)d_out);
}

// Round 13
// 190.020 us; speedup vs baseline: 1.2161x; 1.0825x over previous
//
#include <hip/hip_runtime.h>
#include <hip/hip_bf16.h>

#define B_ 8
#define T_ 1024
#define IN_DIM_ 16
#define D_ 256
#define H_ 8
#define L_ 4
#define DK_ 32
#define BT_ (B_*T_)
#define LDT 72    // padded LDS stride for GEMM A tiles
#define LDO 264   // padded LDS stride for outln A tile (256+8)

typedef __attribute__((ext_vector_type(8))) __bf16 bf16x8;
typedef __attribute__((ext_vector_type(8))) unsigned short u16x8;
typedef __attribute__((ext_vector_type(4))) unsigned short u16x4;
typedef __attribute__((ext_vector_type(4))) float f32x4;
typedef __attribute__((ext_vector_type(4))) unsigned int u32x4;

static __device__ __forceinline__ unsigned short f2bf(float f) {
  union { float f; unsigned int u; } c{f};
  unsigned int u = c.u;
  u += 0x7fff + ((u >> 16) & 1);
  return (unsigned short)(u >> 16);
}
static __device__ __forceinline__ float bf2f(unsigned short s) {
  union { unsigned int u; float f; } c{(unsigned int)s << 16};
  return c.f;
}
static __device__ __forceinline__ bf16x8 as_bf(u16x8 v) {
  return __builtin_bit_cast(bf16x8, v);
}

// ------- weight prep: f32 W[z][K][N] -> bf16 fragment-tiled [z][N/16][K/32][16][32]
__global__ __launch_bounds__(64) void k_wprep_f(
    const float* __restrict__ in, unsigned short* __restrict__ out,
    int K, int N) {
  int nb = blockIdx.x, kb = blockIdx.y, z = blockIdx.z;
  const float* inz = in + (size_t)z * K * N;
  unsigned short* outz = out + (size_t)z * K * N;
  int lane = threadIdx.x;
  int li = lane & 15, g = lane >> 4;
  int n = nb * 16 + li;
  int k0 = kb * 32 + g * 8;
  u16x8 v;
  #pragma unroll
  for (int j = 0; j < 8; ++j) v[j] = f2bf(inz[(k0 + j) * N + n]);
  *(u16x8*)(outz + ((nb * (K >> 5) + kb) << 9) + li * 32 + g * 8) = v;
}

// ---------------- input projection: hbf = bf16(x@Wp + bp + pos) ----------------
__global__ __launch_bounds__(256) void k_proj(
    const float* __restrict__ x, const float* __restrict__ Wp,
    const float* __restrict__ bp, const float* __restrict__ pos,
    unsigned short* __restrict__ hbf) {
  int row = blockIdx.x;            // bt
  int c = threadIdx.x;             // 0..255
  int t = row & (T_ - 1);
  float acc = bp[c] + pos[t * D_ + c];
  const float* xr = x + row * IN_DIM_;
  #pragma unroll
  for (int k = 0; k < IN_DIM_; ++k) acc += xr[k] * Wp[k * D_ + c];
  hbf[row * D_ + c] = f2bf(acc);
}

// ------------- QKV GEMM: BM=128, A staged in LDS, B fragment-tiled from L2 -----
__global__ __launch_bounds__(256) void k_gemm_qkv(
    const unsigned short* __restrict__ A,    // BT x 256 bf16
    const unsigned short* __restrict__ Btf,  // ftiled [48][8][16][32]
    const float* __restrict__ bias,          // 768
    unsigned short* __restrict__ qb, unsigned short* __restrict__ kb,
    unsigned short* __restrict__ vt) {
  __shared__ unsigned short As[128 * LDT];
  int row0 = blockIdx.x * 128;
  int tid = threadIdx.x;
  int lane = tid & 63, w = tid >> 6;
  int g = lane >> 4, li = lane & 15;
  int wr = (w >> 1) * 64, wc = (w & 1) * 32;
  int col0 = blockIdx.y * 64;
  f32x4 acc[4][2] = {};
  for (int k0 = 0; k0 < 256; k0 += 64) {
    __syncthreads();
    int r = tid >> 1, kk = (tid & 1) * 32;
    const unsigned short* src = A + (row0 + r) * 256 + k0 + kk;
    unsigned short* dst = As + r * LDT + kk;
    *(u16x8*)(dst)      = *(const u16x8*)(src);
    *(u16x8*)(dst + 8)  = *(const u16x8*)(src + 8);
    *(u16x8*)(dst + 16) = *(const u16x8*)(src + 16);
    *(u16x8*)(dst + 24) = *(const u16x8*)(src + 24);
    __syncthreads();
    #pragma unroll
    for (int ks = 0; ks < 2; ++ks) {
      int kblk = (k0 >> 5) + ks;
      bf16x8 af[4], bfr[2];
      #pragma unroll
      for (int m = 0; m < 4; ++m)
        af[m] = as_bf(*(const u16x8*)(As + (wr + m * 16 + li) * LDT + ks * 32 + g * 8));
      #pragma unroll
      for (int n = 0; n < 2; ++n) {
        int nblk = (blockIdx.y << 2) + ((w & 1) << 1) + n;
        bfr[n] = as_bf(*(const u16x8*)(Btf + ((nblk * 8 + kblk) << 9) + li * 32 + g * 8));
      }
      #pragma unroll
      for (int m = 0; m < 4; ++m)
        #pragma unroll
        for (int n = 0; n < 2; ++n)
          acc[m][n] = __builtin_amdgcn_mfma_f32_16x16x32_bf16(af[m], bfr[n], acc[m][n], 0, 0, 0);
    }
  }
  const float QSC = 0.25505654f;  // (1/sqrt(32)) * log2(e)
  #pragma unroll
  for (int m = 0; m < 4; ++m)
    #pragma unroll
    for (int n = 0; n < 2; ++n) {
      int c = col0 + wc + n * 16 + li;
      int rbase = row0 + wr + m * 16 + g * 4;
      int b = rbase >> 10, t = rbase & (T_ - 1);
      int s = c >> 8, rem = c & 255, hh = rem >> 5, dk = rem & 31;
      if (s == 0) {
        #pragma unroll
        for (int j = 0; j < 4; ++j) {
          float v = (acc[m][n][j] + bias[c]) * QSC;
          qb[(((b * H_ + hh) * T_) + t + j) * DK_ + dk] = f2bf(v);
        }
      } else if (s == 1) {
        #pragma unroll
        for (int j = 0; j < 4; ++j) {
          float v = acc[m][n][j] + bias[c];
          kb[(((b * H_ + hh) * T_) + t + j) * DK_ + dk] = f2bf(v);
        }
      } else {
        u16x4 pk;
        #pragma unroll
        for (int j = 0; j < 4; ++j) pk[j] = f2bf(acc[m][n][j] + bias[c]);
        // tiled V^T: [bh][t>>5][dk][t&31]
        *(u16x4*)(vt + (b * H_ + hh) * (DK_ * T_) +
                  ((t >> 5) * DK_ + dk) * 32 + (t & 31)) = pk;
      }
    }
}

// ---- attention: 32 q-rows/wave, 4-way split-K, XCD-clustered block remap ----
// 1D grid; id%8 == bh%8 so all q-tiles of one head land on one XCD's L2
// (K+V per XCD = 8 heads x 128KB = 1MB, fits 4MB L2 -> no HBM re-fetch).
__global__ __launch_bounds__(256) void k_attn(
    const unsigned short* __restrict__ qb, const unsigned short* __restrict__ kb,
    const unsigned short* __restrict__ vt, unsigned short* __restrict__ ob) {
  __shared__ float Osh[4][32][33];
  __shared__ float Lsh[4][32];
  int id = blockIdx.x;
  int xcd = id & 7;
  int rest = id >> 3;              // 0..255
  int q0 = (rest & 31) * 32;       // 32 q-tiles
  int bh = ((rest >> 5) << 3) | xcd;  // 64 heads, bh%8 == id%8
  int tid = threadIdx.x, lane = tid & 63, w = tid >> 6;  // w = k-quarter
  int g = lane >> 4, li = lane & 15;
  const unsigned short* Qp = qb + (bh * T_ + q0) * DK_;
  const unsigned short* Kp = kb + bh * T_ * DK_;
  const unsigned short* Vt = vt + bh * DK_ * T_;
  bf16x8 aq0 = as_bf(*(const u16x8*)(Qp + li * DK_ + g * 8));
  bf16x8 aq1 = as_bf(*(const u16x8*)(Qp + (16 + li) * DK_ + g * 8));
  float l_run0 = 0.f, l_run1 = 0.f;
  f32x4 oacc0[2] = {}, oacc1[2] = {};
  for (int kt = w * 256; kt < (w + 1) * 256; kt += 32) {
    bf16x8 bk0 = as_bf(*(const u16x8*)(Kp + (kt + li) * DK_ + g * 8));
    bf16x8 bk1 = as_bf(*(const u16x8*)(Kp + (kt + 16 + li) * DK_ + g * 8));
    const unsigned short* vtile = Vt + (kt >> 5) * (DK_ * 32);
    bf16x8 bv0 = as_bf(*(const u16x8*)(vtile + li * 32 + g * 8));
    bf16x8 bv1 = as_bf(*(const u16x8*)(vtile + (16 + li) * 32 + g * 8));
    f32x4 s0 = {}, s1 = {}, t0 = {}, t1 = {};
    __builtin_amdgcn_s_setprio(1);
    s0 = __builtin_amdgcn_mfma_f32_16x16x32_bf16(bk0, aq0, s0, 0, 0, 0);
    s1 = __builtin_amdgcn_mfma_f32_16x16x32_bf16(bk1, aq0, s1, 0, 0, 0);
    t0 = __builtin_amdgcn_mfma_f32_16x16x32_bf16(bk0, aq1, t0, 0, 0, 0);
    t1 = __builtin_amdgcn_mfma_f32_16x16x32_bf16(bk1, aq1, t1, 0, 0, 0);
    __builtin_amdgcn_s_setprio(0);
    {
      float p0[4], p1[4];
      #pragma unroll
      for (int j = 0; j < 4; ++j) {
        p0[j] = __builtin_amdgcn_exp2f(s0[j]);
        p1[j] = __builtin_amdgcn_exp2f(s1[j]);
      }
      l_run0 += ((p0[0] + p0[1]) + (p0[2] + p0[3])) +
                ((p1[0] + p1[1]) + (p1[2] + p1[3]));
      unsigned int c0, c1, c2, c3;
      asm("v_cvt_pk_bf16_f32 %0, %1, %2" : "=v"(c0) : "v"(p0[0]), "v"(p0[1]));
      asm("v_cvt_pk_bf16_f32 %0, %1, %2" : "=v"(c1) : "v"(p0[2]), "v"(p0[3]));
      asm("v_cvt_pk_bf16_f32 %0, %1, %2" : "=v"(c2) : "v"(p1[0]), "v"(p1[1]));
      asm("v_cvt_pk_bf16_f32 %0, %1, %2" : "=v"(c3) : "v"(p1[2]), "v"(p1[3]));
      asm("v_permlane32_swap_b32 %0, %1" : "+v"(c0), "+v"(c2));
      asm("v_permlane32_swap_b32 %0, %1" : "+v"(c1), "+v"(c3));
      asm("v_permlane16_swap_b32 %0, %1" : "+v"(c0), "+v"(c2));
      asm("v_permlane16_swap_b32 %0, %1" : "+v"(c1), "+v"(c3));
      u32x4 paw; paw[0] = c0; paw[1] = c1; paw[2] = c2; paw[3] = c3;
      bf16x8 pa = __builtin_bit_cast(bf16x8, paw);
      __builtin_amdgcn_s_setprio(1);
      oacc0[0] = __builtin_amdgcn_mfma_f32_16x16x32_bf16(pa, bv0, oacc0[0], 0, 0, 0);
      oacc0[1] = __builtin_amdgcn_mfma_f32_16x16x32_bf16(pa, bv1, oacc0[1], 0, 0, 0);
      __builtin_amdgcn_s_setprio(0);
    }
    {
      float p0[4], p1[4];
      #pragma unroll
      for (int j = 0; j < 4; ++j) {
        p0[j] = __builtin_amdgcn_exp2f(t0[j]);
        p1[j] = __builtin_amdgcn_exp2f(t1[j]);
      }
      l_run1 += ((p0[0] + p0[1]) + (p0[2] + p0[3])) +
                ((p1[0] + p1[1]) + (p1[2] + p1[3]));
      unsigned int c0, c1, c2, c3;
      asm("v_cvt_pk_bf16_f32 %0, %1, %2" : "=v"(c0) : "v"(p0[0]), "v"(p0[1]));
      asm("v_cvt_pk_bf16_f32 %0, %1, %2" : "=v"(c1) : "v"(p0[2]), "v"(p0[3]));
      asm("v_cvt_pk_bf16_f32 %0, %1, %2" : "=v"(c2) : "v"(p1[0]), "v"(p1[1]));
      asm("v_cvt_pk_bf16_f32 %0, %1, %2" : "=v"(c3) : "v"(p1[2]), "v"(p1[3]));
      asm("v_permlane32_swap_b32 %0, %1" : "+v"(c0), "+v"(c2));
      asm("v_permlane32_swap_b32 %0, %1" : "+v"(c1), "+v"(c3));
      asm("v_permlane16_swap_b32 %0, %1" : "+v"(c0), "+v"(c2));
      asm("v_permlane16_swap_b32 %0, %1" : "+v"(c1), "+v"(c3));
      u32x4 paw; paw[0] = c0; paw[1] = c1; paw[2] = c2; paw[3] = c3;
      bf16x8 pa = __builtin_bit_cast(bf16x8, paw);
      __builtin_amdgcn_s_setprio(1);
      oacc1[0] = __builtin_amdgcn_mfma_f32_16x16x32_bf16(pa, bv0, oacc1[0], 0, 0, 0);
      oacc1[1] = __builtin_amdgcn_mfma_f32_16x16x32_bf16(pa, bv1, oacc1[1], 0, 0, 0);
      __builtin_amdgcn_s_setprio(0);
    }
  }
  l_run0 += __shfl_xor(l_run0, 16);
  l_run0 += __shfl_xor(l_run0, 32);
  l_run1 += __shfl_xor(l_run1, 16);
  l_run1 += __shfl_xor(l_run1, 32);
  if (g == 0) { Lsh[w][li] = l_run0; Lsh[w][16 + li] = l_run1; }
  #pragma unroll
  for (int dh = 0; dh < 2; ++dh)
    #pragma unroll
    for (int j = 0; j < 4; ++j) {
      Osh[w][g * 4 + j][dh * 16 + li] = oacc0[dh][j];
      Osh[w][16 + g * 4 + j][dh * 16 + li] = oacc1[dh][j];
    }
  __syncthreads();
  if (tid < 128) {
    int q = tid & 31, dk0 = (tid >> 5) * 8;
    float l = (Lsh[0][q] + Lsh[1][q]) + (Lsh[2][q] + Lsh[3][q]);
    float rl = 1.0f / l;
    int b = bh >> 3, hh = bh & 7;
    u16x8 outv;
    #pragma unroll
    for (int i = 0; i < 8; ++i) {
      float o = (Osh[0][q][dk0 + i] + Osh[1][q][dk0 + i]) +
                (Osh[2][q][dk0 + i] + Osh[3][q][dk0 + i]);
      outv[i] = f2bf(o * rl);
    }
    *(u16x8*)(ob + ((b * T_ + q0 + q) * H_ + hh) * DK_ + dk0) = outv;
  }
}

// -- fused out-proj + residual + LayerNorm, bf16 residual: hbf = LN(ob@W+b+hbf) --
__global__ __launch_bounds__(256) void k_outln(
    const unsigned short* __restrict__ A,    // BT x 256 bf16 (attn out)
    const unsigned short* __restrict__ Btf,  // ftiled [16][8][16][32]
    const float* __restrict__ bias,          // 256
    const float* __restrict__ gg, const float* __restrict__ bb,
    unsigned short* __restrict__ hbf) {      // in: residual, out: LN result
  __shared__ unsigned short Asp[32 * LDO];
  __shared__ float Ssh[2][2][16], Qsh[2][2][16];
  int tid = threadIdx.x, lane = tid & 63, w = tid >> 6;
  int g = lane >> 4, li = lane & 15;
  int rg = w >> 1, ch = w & 1;
  int row0 = blockIdx.x * 32;
  int c0 = ch * 128;
  {  // stage A tile 32x256 coalesced
    int r = tid >> 3, kk = (tid & 7) * 32;
    const unsigned short* src = A + (row0 + r) * 256 + kk;
    unsigned short* dst = Asp + r * LDO + kk;
    *(u16x8*)(dst)      = *(const u16x8*)(src);
    *(u16x8*)(dst + 8)  = *(const u16x8*)(src + 8);
    *(u16x8*)(dst + 16) = *(const u16x8*)(src + 16);
    *(u16x8*)(dst + 24) = *(const u16x8*)(src + 24);
  }
  __syncthreads();
  int rowb = rg * 16;
  f32x4 acc[8] = {};
  for (int k0 = 0; k0 < 256; k0 += 32) {
    int kblk = k0 >> 5;
    bf16x8 af = as_bf(*(const u16x8*)(Asp + (rowb + li) * LDO + k0 + g * 8));
    #pragma unroll
    for (int n = 0; n < 8; ++n) {
      int nblk = ch * 8 + n;
      bf16x8 bf = as_bf(*(const u16x8*)(Btf + ((nblk * 8 + kblk) << 9) + li * 32 + g * 8));
      acc[n] = __builtin_amdgcn_mfma_f32_16x16x32_bf16(af, bf, acc[n], 0, 0, 0);
    }
  }
  int row0w = row0 + rowb;
  float uv[8][4];
  float s[4] = {0.f, 0.f, 0.f, 0.f}, q[4] = {0.f, 0.f, 0.f, 0.f};
  #pragma unroll
  for (int n = 0; n < 8; ++n) {
    int c = c0 + n * 16 + li;
    float bs = bias[c];
    #pragma unroll
    for (int j = 0; j < 4; ++j) {
      int r = row0w + g * 4 + j;
      float v = acc[n][j] + bs + bf2f(hbf[r * 256 + c]);
      uv[n][j] = v;
      s[j] += v; q[j] += v * v;
    }
  }
  #pragma unroll
  for (int j = 0; j < 4; ++j) {
    #pragma unroll
    for (int o = 1; o < 16; o <<= 1) {
      s[j] += __shfl_xor(s[j], o);
      q[j] += __shfl_xor(q[j], o);
    }
  }
  if (li == 0) {
    #pragma unroll
    for (int j = 0; j < 4; ++j) {
      Ssh[rg][ch][g * 4 + j] = s[j];
      Qsh[rg][ch][g * 4 + j] = q[j];
    }
  }
  __syncthreads();
  #pragma unroll
  for (int j = 0; j < 4; ++j) {
    int r = g * 4 + j;
    float st = Ssh[rg][0][r] + Ssh[rg][1][r];
    float qt = Qsh[rg][0][r] + Qsh[rg][1][r];
    float mean = st * (1.0f / D_);
    float var = qt * (1.0f / D_) - mean * mean;
    float rstd = rsqrtf(var + 1e-5f);
    s[j] = mean; q[j] = rstd;
  }
  #pragma unroll
  for (int n = 0; n < 8; ++n) {
    int c = c0 + n * 16 + li;
    float gv = gg[c], bv = bb[c];
    #pragma unroll
    for (int j = 0; j < 4; ++j) {
      int r = row0w + g * 4 + j;
      float y = (uv[n][j] - s[j]) * q[j] * gv + bv;
      hbf[r * 256 + c] = f2bf(y);
    }
  }
}

// ---------------- final: out = h[:, -1, :] @ Wo + bo (h from bf16) ----------------
__global__ void k_final(const unsigned short* __restrict__ hbf,
                        const float* __restrict__ Wo,
                        const float* __restrict__ bo, float* __restrict__ out) {
  int tid = threadIdx.x;
  if (tid >= B_ * 3) return;
  int b = tid / 3, j = tid % 3;
  const unsigned short* hr = hbf + (b * T_ + (T_ - 1)) * D_;
  float acc = bo[j];
  for (int k = 0; k < D_; ++k) acc += bf2f(hr[k]) * Wo[k * 3 + j];
  out[tid] = acc;
}

extern "C" void kernel_launch(void* const* d_in, const int* in_sizes, int n_in,
                              void* d_out, int out_size, void* d_ws, size_t ws_size,
                              hipStream_t stream) {
  const float* x    = (const float*)d_in[0];
  const float* Wp   = (const float*)d_in[1];
  const float* bp   = (const float*)d_in[2];
  const float* pos  = (const float*)d_in[3];
  const float* Wqkv = (const float*)d_in[4];
  const float* bqkv = (const float*)d_in[5];
  const float* Wout = (const float*)d_in[6];
  const float* bout = (const float*)d_in[7];
  const float* ln_g = (const float*)d_in[8];
  const float* ln_b = (const float*)d_in[9];
  const float* Wo   = (const float*)d_in[10];
  const float* bo   = (const float*)d_in[11];

  char* ws = (char*)d_ws;
  unsigned short* hbf = (unsigned short*)(ws);               // 4 MB (bf16 h)
  unsigned short* qb  = (unsigned short*)(ws + (4u << 20));  // 4 MB
  unsigned short* kb  = (unsigned short*)(ws + (8u << 20));  // 4 MB
  unsigned short* vt  = (unsigned short*)(ws + (12u << 20)); // 4 MB (tiled V^T)
  unsigned short* ob  = (unsigned short*)(ws + (16u << 20)); // 4 MB
  unsigned short* WqkvT = (unsigned short*)(ws + (20u << 20)); // 1.5 MB ftiled
  unsigned short* WoutT = (unsigned short*)(ws + (22u << 20)); // 0.5 MB ftiled

  k_wprep_f<<<dim3(48, 8, 4), 64, 0, stream>>>(Wqkv, WqkvT, 256, 768);
  k_wprep_f<<<dim3(16, 8, 4), 64, 0, stream>>>(Wout, WoutT, 256, 256);
  k_proj<<<BT_, 256, 0, stream>>>(x, Wp, bp, pos, hbf);
  for (int l = 0; l < L_; ++l) {
    k_gemm_qkv<<<dim3(BT_ / 128, 12), 256, 0, stream>>>(
        hbf, WqkvT + l * 768 * 256, bqkv + l * 768, qb, kb, vt);
    k_attn<<<dim3(2048), 256, 0, stream>>>(qb, kb, vt, ob);
    k_outln<<<BT_ / 32, 256, 0, stream>>>(
        ob, WoutT + l * 256 * 256, bout + l * 256,
        ln_g + l * 256, ln_b + l * 256, hbf);
  }
  k_final<<<1, 64, 0, stream>>>(hbf, Wo, bo, (float*)d_out);
}

// Round 14
// 184.952 us; speedup vs baseline: 1.2494x; 1.0274x over previous
//
#include <hip/hip_runtime.h>
#include <hip/hip_bf16.h>

#define B_ 8
#define T_ 1024
#define IN_DIM_ 16
#define D_ 256
#define H_ 8
#define L_ 4
#define DK_ 32
#define BT_ (B_*T_)
#define LDT 72    // padded LDS stride for GEMM A tiles
#define LDO 264   // padded LDS stride for outln A tile (256+8)

typedef __attribute__((ext_vector_type(8))) __bf16 bf16x8;
typedef __attribute__((ext_vector_type(8))) unsigned short u16x8;
typedef __attribute__((ext_vector_type(4))) unsigned short u16x4;
typedef __attribute__((ext_vector_type(4))) float f32x4;
typedef __attribute__((ext_vector_type(4))) unsigned int u32x4;

static __device__ __forceinline__ unsigned short f2bf(float f) {
  union { float f; unsigned int u; } c{f};
  unsigned int u = c.u;
  u += 0x7fff + ((u >> 16) & 1);
  return (unsigned short)(u >> 16);
}
static __device__ __forceinline__ float bf2f(unsigned short s) {
  union { unsigned int u; float f; } c{(unsigned int)s << 16};
  return c.f;
}
static __device__ __forceinline__ bf16x8 as_bf(u16x8 v) {
  return __builtin_bit_cast(bf16x8, v);
}

// ------- weight prep (both weights, one launch): f32 W[z][K][N] -> bf16
// fragment-tiled [z][N/16][K/32][16][32]
__global__ __launch_bounds__(64) void k_wprep2(
    const float* __restrict__ wqkv, unsigned short* __restrict__ oq,
    const float* __restrict__ wout, unsigned short* __restrict__ oo) {
  int z = blockIdx.z;
  int K = 256;
  int N; const float* inz; unsigned short* outz;
  if (z < 4) {
    N = 768; inz = wqkv + (size_t)z * K * N; outz = oq + (size_t)z * K * N;
  } else {
    N = 256;
    if (blockIdx.x >= 16) return;
    inz = wout + (size_t)(z - 4) * K * N; outz = oo + (size_t)(z - 4) * K * N;
  }
  int nb = blockIdx.x, kb = blockIdx.y;
  int lane = threadIdx.x;
  int li = lane & 15, g = lane >> 4;
  int n = nb * 16 + li;
  int k0 = kb * 32 + g * 8;
  u16x8 v;
  #pragma unroll
  for (int j = 0; j < 8; ++j) v[j] = f2bf(inz[(k0 + j) * N + n]);
  *(u16x8*)(outz + ((nb * (K >> 5) + kb) << 9) + li * 32 + g * 8) = v;
}

// ---------------- input projection: hbf = bf16(x@Wp + bp + pos) ----------------
__global__ __launch_bounds__(256) void k_proj(
    const float* __restrict__ x, const float* __restrict__ Wp,
    const float* __restrict__ bp, const float* __restrict__ pos,
    unsigned short* __restrict__ hbf) {
  int row = blockIdx.x;            // bt
  int c = threadIdx.x;             // 0..255
  int t = row & (T_ - 1);
  float acc = bp[c] + pos[t * D_ + c];
  const float* xr = x + row * IN_DIM_;
  #pragma unroll
  for (int k = 0; k < IN_DIM_; ++k) acc += xr[k] * Wp[k * D_ + c];
  hbf[row * D_ + c] = f2bf(acc);
}

// ------------- QKV GEMM: BM=128, A staged in LDS, B fragment-tiled from L2 -----
__global__ __launch_bounds__(256) void k_gemm_qkv(
    const unsigned short* __restrict__ A,    // BT x 256 bf16
    const unsigned short* __restrict__ Btf,  // ftiled [48][8][16][32]
    const float* __restrict__ bias,          // 768
    unsigned short* __restrict__ qb, unsigned short* __restrict__ kb,
    unsigned short* __restrict__ vt) {
  __shared__ unsigned short As[128 * LDT];
  int row0 = blockIdx.x * 128;
  int tid = threadIdx.x;
  int lane = tid & 63, w = tid >> 6;
  int g = lane >> 4, li = lane & 15;
  int wr = (w >> 1) * 64, wc = (w & 1) * 32;
  int col0 = blockIdx.y * 64;
  f32x4 acc[4][2] = {};
  for (int k0 = 0; k0 < 256; k0 += 64) {
    __syncthreads();
    int r = tid >> 1, kk = (tid & 1) * 32;
    const unsigned short* src = A + (row0 + r) * 256 + k0 + kk;
    unsigned short* dst = As + r * LDT + kk;
    *(u16x8*)(dst)      = *(const u16x8*)(src);
    *(u16x8*)(dst + 8)  = *(const u16x8*)(src + 8);
    *(u16x8*)(dst + 16) = *(const u16x8*)(src + 16);
    *(u16x8*)(dst + 24) = *(const u16x8*)(src + 24);
    __syncthreads();
    #pragma unroll
    for (int ks = 0; ks < 2; ++ks) {
      int kblk = (k0 >> 5) + ks;
      bf16x8 af[4], bfr[2];
      #pragma unroll
      for (int m = 0; m < 4; ++m)
        af[m] = as_bf(*(const u16x8*)(As + (wr + m * 16 + li) * LDT + ks * 32 + g * 8));
      #pragma unroll
      for (int n = 0; n < 2; ++n) {
        int nblk = (blockIdx.y << 2) + ((w & 1) << 1) + n;
        bfr[n] = as_bf(*(const u16x8*)(Btf + ((nblk * 8 + kblk) << 9) + li * 32 + g * 8));
      }
      #pragma unroll
      for (int m = 0; m < 4; ++m)
        #pragma unroll
        for (int n = 0; n < 2; ++n)
          acc[m][n] = __builtin_amdgcn_mfma_f32_16x16x32_bf16(af[m], bfr[n], acc[m][n], 0, 0, 0);
    }
  }
  const float QSC = 0.25505654f;  // (1/sqrt(32)) * log2(e)
  #pragma unroll
  for (int m = 0; m < 4; ++m)
    #pragma unroll
    for (int n = 0; n < 2; ++n) {
      int c = col0 + wc + n * 16 + li;
      int rbase = row0 + wr + m * 16 + g * 4;
      int b = rbase >> 10, t = rbase & (T_ - 1);
      int s = c >> 8, rem = c & 255, hh = rem >> 5, dk = rem & 31;
      if (s == 0) {
        #pragma unroll
        for (int j = 0; j < 4; ++j) {
          float v = (acc[m][n][j] + bias[c]) * QSC;
          qb[(((b * H_ + hh) * T_) + t + j) * DK_ + dk] = f2bf(v);
        }
      } else if (s == 1) {
        #pragma unroll
        for (int j = 0; j < 4; ++j) {
          float v = acc[m][n][j] + bias[c];
          kb[(((b * H_ + hh) * T_) + t + j) * DK_ + dk] = f2bf(v);
        }
      } else {
        u16x4 pk;
        #pragma unroll
        for (int j = 0; j < 4; ++j) pk[j] = f2bf(acc[m][n][j] + bias[c]);
        // tiled V^T: [bh][t>>5][dk][t&31]
        *(u16x4*)(vt + (b * H_ + hh) * (DK_ * T_) +
                  ((t >> 5) * DK_ + dk) * 32 + (t & 31)) = pk;
      }
    }
}

// softmax (exp2, no max) + in-register P transpose + PV for one 32-k sub-block
#define SOFTPV(sA, sB, lrun, bvA, bvB, oac)                                     \
  {                                                                             \
    float p0[4], p1[4];                                                         \
    _Pragma("unroll")                                                           \
    for (int j = 0; j < 4; ++j) {                                               \
      p0[j] = __builtin_amdgcn_exp2f(sA[j]);                                    \
      p1[j] = __builtin_amdgcn_exp2f(sB[j]);                                    \
    }                                                                           \
    lrun += ((p0[0] + p0[1]) + (p0[2] + p0[3])) +                               \
            ((p1[0] + p1[1]) + (p1[2] + p1[3]));                                \
    unsigned int c0, c1, c2, c3;                                                \
    asm("v_cvt_pk_bf16_f32 %0, %1, %2" : "=v"(c0) : "v"(p0[0]), "v"(p0[1]));    \
    asm("v_cvt_pk_bf16_f32 %0, %1, %2" : "=v"(c1) : "v"(p0[2]), "v"(p0[3]));    \
    asm("v_cvt_pk_bf16_f32 %0, %1, %2" : "=v"(c2) : "v"(p1[0]), "v"(p1[1]));    \
    asm("v_cvt_pk_bf16_f32 %0, %1, %2" : "=v"(c3) : "v"(p1[2]), "v"(p1[3]));    \
    asm("v_permlane32_swap_b32 %0, %1" : "+v"(c0), "+v"(c2));                   \
    asm("v_permlane32_swap_b32 %0, %1" : "+v"(c1), "+v"(c3));                   \
    asm("v_permlane16_swap_b32 %0, %1" : "+v"(c0), "+v"(c2));                   \
    asm("v_permlane16_swap_b32 %0, %1" : "+v"(c1), "+v"(c3));                   \
    u32x4 paw; paw[0] = c0; paw[1] = c1; paw[2] = c2; paw[3] = c3;              \
    bf16x8 pa = __builtin_bit_cast(bf16x8, paw);                                \
    __builtin_amdgcn_s_setprio(1);                                              \
    oac[0] = __builtin_amdgcn_mfma_f32_16x16x32_bf16(pa, bvA, oac[0], 0, 0, 0); \
    oac[1] = __builtin_amdgcn_mfma_f32_16x16x32_bf16(pa, bvB, oac[1], 0, 0, 0); \
    __builtin_amdgcn_s_setprio(0);                                              \
  }

// ---- attention: 32 q-rows/wave, 4-way split-K, KVBLK=64, XCD-clustered ----
// id%8 == bh%8 so all q-tiles of a head land on one XCD's L2. Per iteration:
// 8 K/V loads issued up front, QK+softmax+PV split per 32-k sub-block (A then
// B) so score regs don't all coexist; B loads land under A compute.
__global__ __launch_bounds__(256) void k_attn(
    const unsigned short* __restrict__ qb, const unsigned short* __restrict__ kb,
    const unsigned short* __restrict__ vt, unsigned short* __restrict__ ob) {
  __shared__ float Osh[4][32][33];
  __shared__ float Lsh[4][32];
  int id = blockIdx.x;
  int xcd = id & 7;
  int rest = id >> 3;              // 0..255
  int q0 = (rest & 31) * 32;       // 32 q-tiles
  int bh = ((rest >> 5) << 3) | xcd;  // 64 heads, bh%8 == id%8
  int tid = threadIdx.x, lane = tid & 63, w = tid >> 6;  // w = k-quarter
  int g = lane >> 4, li = lane & 15;
  const unsigned short* Qp = qb + (bh * T_ + q0) * DK_;
  const unsigned short* Kp = kb + bh * T_ * DK_;
  const unsigned short* Vt = vt + bh * DK_ * T_;
  bf16x8 aq0 = as_bf(*(const u16x8*)(Qp + li * DK_ + g * 8));
  bf16x8 aq1 = as_bf(*(const u16x8*)(Qp + (16 + li) * DK_ + g * 8));
  float l_run0 = 0.f, l_run1 = 0.f;
  f32x4 oacc0[2] = {}, oacc1[2] = {};
  for (int kt = w * 256; kt < (w + 1) * 256; kt += 64) {
    // all 8 loads up front (1KB coalesced segments each)
    const unsigned short* kpA = Kp + kt * DK_;
    bf16x8 bk0 = as_bf(*(const u16x8*)(kpA + li * DK_ + g * 8));
    bf16x8 bk1 = as_bf(*(const u16x8*)(kpA + (16 + li) * DK_ + g * 8));
    bf16x8 bk2 = as_bf(*(const u16x8*)(kpA + (32 + li) * DK_ + g * 8));
    bf16x8 bk3 = as_bf(*(const u16x8*)(kpA + (48 + li) * DK_ + g * 8));
    const unsigned short* vtA = Vt + (kt >> 5) * (DK_ * 32);
    bf16x8 bv0 = as_bf(*(const u16x8*)(vtA + li * 32 + g * 8));
    bf16x8 bv1 = as_bf(*(const u16x8*)(vtA + (16 + li) * 32 + g * 8));
    bf16x8 bv2 = as_bf(*(const u16x8*)(vtA + DK_ * 32 + li * 32 + g * 8));
    bf16x8 bv3 = as_bf(*(const u16x8*)(vtA + DK_ * 32 + (16 + li) * 32 + g * 8));
    // sub-block A (k = kt..kt+31)
    {
      f32x4 s0 = {}, s1 = {}, t0 = {}, t1 = {};
      __builtin_amdgcn_s_setprio(1);
      s0 = __builtin_amdgcn_mfma_f32_16x16x32_bf16(bk0, aq0, s0, 0, 0, 0);
      s1 = __builtin_amdgcn_mfma_f32_16x16x32_bf16(bk1, aq0, s1, 0, 0, 0);
      t0 = __builtin_amdgcn_mfma_f32_16x16x32_bf16(bk0, aq1, t0, 0, 0, 0);
      t1 = __builtin_amdgcn_mfma_f32_16x16x32_bf16(bk1, aq1, t1, 0, 0, 0);
      __builtin_amdgcn_s_setprio(0);
      SOFTPV(s0, s1, l_run0, bv0, bv1, oacc0);
      SOFTPV(t0, t1, l_run1, bv0, bv1, oacc1);
    }
    // sub-block B (k = kt+32..kt+63)
    {
      f32x4 s2 = {}, s3 = {}, t2 = {}, t3 = {};
      __builtin_amdgcn_s_setprio(1);
      s2 = __builtin_amdgcn_mfma_f32_16x16x32_bf16(bk2, aq0, s2, 0, 0, 0);
      s3 = __builtin_amdgcn_mfma_f32_16x16x32_bf16(bk3, aq0, s3, 0, 0, 0);
      t2 = __builtin_amdgcn_mfma_f32_16x16x32_bf16(bk2, aq1, t2, 0, 0, 0);
      t3 = __builtin_amdgcn_mfma_f32_16x16x32_bf16(bk3, aq1, t3, 0, 0, 0);
      __builtin_amdgcn_s_setprio(0);
      SOFTPV(s2, s3, l_run0, bv2, bv3, oacc0);
      SOFTPV(t2, t3, l_run1, bv2, bv3, oacc1);
    }
  }
  l_run0 += __shfl_xor(l_run0, 16);
  l_run0 += __shfl_xor(l_run0, 32);
  l_run1 += __shfl_xor(l_run1, 16);
  l_run1 += __shfl_xor(l_run1, 32);
  if (g == 0) { Lsh[w][li] = l_run0; Lsh[w][16 + li] = l_run1; }
  #pragma unroll
  for (int dh = 0; dh < 2; ++dh)
    #pragma unroll
    for (int j = 0; j < 4; ++j) {
      Osh[w][g * 4 + j][dh * 16 + li] = oacc0[dh][j];
      Osh[w][16 + g * 4 + j][dh * 16 + li] = oacc1[dh][j];
    }
  __syncthreads();
  if (tid < 128) {
    int q = tid & 31, dk0 = (tid >> 5) * 8;
    float l = (Lsh[0][q] + Lsh[1][q]) + (Lsh[2][q] + Lsh[3][q]);
    float rl = 1.0f / l;
    int b = bh >> 3, hh = bh & 7;
    u16x8 outv;
    #pragma unroll
    for (int i = 0; i < 8; ++i) {
      float o = (Osh[0][q][dk0 + i] + Osh[1][q][dk0 + i]) +
                (Osh[2][q][dk0 + i] + Osh[3][q][dk0 + i]);
      outv[i] = f2bf(o * rl);
    }
    *(u16x8*)(ob + ((b * T_ + q0 + q) * H_ + hh) * DK_ + dk0) = outv;
  }
}

// -- fused out-proj + residual + LayerNorm, bf16 residual: hbf = LN(ob@W+b+hbf) --
__global__ __launch_bounds__(256) void k_outln(
    const unsigned short* __restrict__ A,    // BT x 256 bf16 (attn out)
    const unsigned short* __restrict__ Btf,  // ftiled [16][8][16][32]
    const float* __restrict__ bias,          // 256
    const float* __restrict__ gg, const float* __restrict__ bb,
    unsigned short* __restrict__ hbf) {      // in: residual, out: LN result
  __shared__ unsigned short Asp[32 * LDO];
  __shared__ float Ssh[2][2][16], Qsh[2][2][16];
  int tid = threadIdx.x, lane = tid & 63, w = tid >> 6;
  int g = lane >> 4, li = lane & 15;
  int rg = w >> 1, ch = w & 1;
  int row0 = blockIdx.x * 32;
  int c0 = ch * 128;
  {  // stage A tile 32x256 coalesced
    int r = tid >> 3, kk = (tid & 7) * 32;
    const unsigned short* src = A + (row0 + r) * 256 + kk;
    unsigned short* dst = Asp + r * LDO + kk;
    *(u16x8*)(dst)      = *(const u16x8*)(src);
    *(u16x8*)(dst + 8)  = *(const u16x8*)(src + 8);
    *(u16x8*)(dst + 16) = *(const u16x8*)(src + 16);
    *(u16x8*)(dst + 24) = *(const u16x8*)(src + 24);
  }
  __syncthreads();
  int rowb = rg * 16;
  f32x4 acc[8] = {};
  for (int k0 = 0; k0 < 256; k0 += 32) {
    int kblk = k0 >> 5;
    bf16x8 af = as_bf(*(const u16x8*)(Asp + (rowb + li) * LDO + k0 + g * 8));
    #pragma unroll
    for (int n = 0; n < 8; ++n) {
      int nblk = ch * 8 + n;
      bf16x8 bf = as_bf(*(const u16x8*)(Btf + ((nblk * 8 + kblk) << 9) + li * 32 + g * 8));
      acc[n] = __builtin_amdgcn_mfma_f32_16x16x32_bf16(af, bf, acc[n], 0, 0, 0);
    }
  }
  int row0w = row0 + rowb;
  float uv[8][4];
  float s[4] = {0.f, 0.f, 0.f, 0.f}, q[4] = {0.f, 0.f, 0.f, 0.f};
  #pragma unroll
  for (int n = 0; n < 8; ++n) {
    int c = c0 + n * 16 + li;
    float bs = bias[c];
    #pragma unroll
    for (int j = 0; j < 4; ++j) {
      int r = row0w + g * 4 + j;
      float v = acc[n][j] + bs + bf2f(hbf[r * 256 + c]);
      uv[n][j] = v;
      s[j] += v; q[j] += v * v;
    }
  }
  #pragma unroll
  for (int j = 0; j < 4; ++j) {
    #pragma unroll
    for (int o = 1; o < 16; o <<= 1) {
      s[j] += __shfl_xor(s[j], o);
      q[j] += __shfl_xor(q[j], o);
    }
  }
  if (li == 0) {
    #pragma unroll
    for (int j = 0; j < 4; ++j) {
      Ssh[rg][ch][g * 4 + j] = s[j];
      Qsh[rg][ch][g * 4 + j] = q[j];
    }
  }
  __syncthreads();
  #pragma unroll
  for (int j = 0; j < 4; ++j) {
    int r = g * 4 + j;
    float st = Ssh[rg][0][r] + Ssh[rg][1][r];
    float qt = Qsh[rg][0][r] + Qsh[rg][1][r];
    float mean = st * (1.0f / D_);
    float var = qt * (1.0f / D_) - mean * mean;
    float rstd = rsqrtf(var + 1e-5f);
    s[j] = mean; q[j] = rstd;
  }
  #pragma unroll
  for (int n = 0; n < 8; ++n) {
    int c = c0 + n * 16 + li;
    float gv = gg[c], bv = bb[c];
    #pragma unroll
    for (int j = 0; j < 4; ++j) {
      int r = row0w + g * 4 + j;
      float y = (uv[n][j] - s[j]) * q[j] * gv + bv;
      hbf[r * 256 + c] = f2bf(y);
    }
  }
}

// ---------------- final: out = h[:, -1, :] @ Wo + bo (h from bf16) ----------------
__global__ void k_final(const unsigned short* __restrict__ hbf,
                        const float* __restrict__ Wo,
                        const float* __restrict__ bo, float* __restrict__ out) {
  int tid = threadIdx.x;
  if (tid >= B_ * 3) return;
  int b = tid / 3, j = tid % 3;
  const unsigned short* hr = hbf + (b * T_ + (T_ - 1)) * D_;
  float acc = bo[j];
  for (int k = 0; k < D_; ++k) acc += bf2f(hr[k]) * Wo[k * 3 + j];
  out[tid] = acc;
}

extern "C" void kernel_launch(void* const* d_in, const int* in_sizes, int n_in,
                              void* d_out, int out_size, void* d_ws, size_t ws_size,
                              hipStream_t stream) {
  const float* x    = (const float*)d_in[0];
  const float* Wp   = (const float*)d_in[1];
  const float* bp   = (const float*)d_in[2];
  const float* pos  = (const float*)d_in[3];
  const float* Wqkv = (const float*)d_in[4];
  const float* bqkv = (const float*)d_in[5];
  const float* Wout = (const float*)d_in[6];
  const float* bout = (const float*)d_in[7];
  const float* ln_g = (const float*)d_in[8];
  const float* ln_b = (const float*)d_in[9];
  const float* Wo   = (const float*)d_in[10];
  const float* bo   = (const float*)d_in[11];

  char* ws = (char*)d_ws;
  unsigned short* hbf = (unsigned short*)(ws);               // 4 MB (bf16 h)
  unsigned short* qb  = (unsigned short*)(ws + (4u << 20));  // 4 MB
  unsigned short* kb  = (unsigned short*)(ws + (8u << 20));  // 4 MB
  unsigned short* vt  = (unsigned short*)(ws + (12u << 20)); // 4 MB (tiled V^T)
  unsigned short* ob  = (unsigned short*)(ws + (16u << 20)); // 4 MB
  unsigned short* WqkvT = (unsigned short*)(ws + (20u << 20)); // 1.5 MB ftiled
  unsigned short* WoutT = (unsigned short*)(ws + (22u << 20)); // 0.5 MB ftiled

  k_wprep2<<<dim3(48, 8, 8), 64, 0, stream>>>(Wqkv, WqkvT, Wout, WoutT);
  k_proj<<<BT_, 256, 0, stream>>>(x, Wp, bp, pos, hbf);
  for (int l = 0; l < L_; ++l) {
    k_gemm_qkv<<<dim3(BT_ / 128, 12), 256, 0, stream>>>(
        hbf, WqkvT + l * 768 * 256, bqkv + l * 768, qb, kb, vt);
    k_attn<<<dim3(2048), 256, 0, stream>>>(qb, kb, vt, ob);
    k_outln<<<BT_ / 32, 256, 0, stream>>>(
        ob, WoutT + l * 256 * 256, bout + l * 256,
        ln_g + l * 256, ln_b + l * 256, hbf);
  }
  k_final<<<1, 64, 0, stream>>>(hbf, Wo, bo, (float*)d_out);
}